// Round 1
// baseline (97.263 us; speedup 1.0000x reference)
//
#include <hip/hip_runtime.h>

// FWHT, natural (Sylvester) order: out[c] = sum_j (-1)^popcount(c&j) x[j]
// D = 4096 = 16*16*16 -> three in-register W16 phases + two LDS digit swaps.

__device__ __forceinline__ void wht16(float v[16]) {
#pragma unroll
    for (int h = 1; h < 16; h <<= 1) {
#pragma unroll
        for (int i = 0; i < 16; i++) {
            if ((i & h) == 0) {
                float a = v[i];
                float b = v[i ^ h];
                v[i]     = a + b;
                v[i ^ h] = a - b;
            }
        }
    }
}

__global__ __launch_bounds__(256) void fwht4096_kernel(const float* __restrict__ in,
                                                       float* __restrict__ out) {
    // padded LDS: logical j in [0,4096) stored at (j>>4)*17 + (j&15)
    __shared__ float lds[256 * 17];

    const int row = blockIdx.x;
    const int t   = threadIdx.x;

    const float* rp = in + (size_t)row * 4096;
    float v[16];

    // ---- load: thread t owns j = t*16 + r (contiguous 64B -> 4x float4) ----
    const float4* p4 = (const float4*)(rp + t * 16);
#pragma unroll
    for (int q = 0; q < 4; q++) {
        float4 f = p4[q];
        v[4 * q + 0] = f.x;
        v[4 * q + 1] = f.y;
        v[4 * q + 2] = f.z;
        v[4 * q + 3] = f.w;
    }

    // ---- phase 1: W16 over bits 0-3 (r) ----
    wht16(v);

    // ---- exchange 1: j = t*16 + r  ->  thread holds varying bits 4-7 ----
#pragma unroll
    for (int r = 0; r < 16; r++) lds[t * 17 + r] = v[r];
    __syncthreads();

    const int u_hi = t >> 4;   // becomes bits 8-11
    const int u_lo = t & 15;   // becomes bits 0-3
#pragma unroll
    for (int k = 0; k < 16; k++) v[k] = lds[(u_hi * 16 + k) * 17 + u_lo];

    // ---- phase 2: W16 over bits 4-7 ----
    wht16(v);

    // ---- exchange 2: write back to the exact slots this thread read (no race,
    //      no sync needed before the write), then re-read along bits 8-11 ----
#pragma unroll
    for (int k = 0; k < 16; k++) lds[(u_hi * 16 + k) * 17 + u_lo] = v[k];
    __syncthreads();

#pragma unroll
    for (int m = 0; m < 16; m++) v[m] = lds[(m * 16 + u_hi) * 17 + u_lo];

    // ---- phase 3: W16 over bits 8-11 ----
    wht16(v);

    // ---- store: thread holds j = m*256 + t  -> per-m wave-contiguous 256B ----
    float* op = out + (size_t)row * 4096 + t;
#pragma unroll
    for (int m = 0; m < 16; m++) op[m * 256] = v[m];
}

extern "C" void kernel_launch(void* const* d_in, const int* in_sizes, int n_in,
                              void* d_out, int out_size, void* d_ws, size_t ws_size,
                              hipStream_t stream) {
    const float* x = (const float*)d_in[0];
    float* out     = (float*)d_out;
    const int rows = in_sizes[0] / 4096;   // 16384
    fwht4096_kernel<<<dim3(rows), dim3(256), 0, stream>>>(x, out);
}